// Round 8
// baseline (100.466 us; speedup 1.0000x reference)
//
#include <hip/hip_runtime.h>
#include <math.h>

#define NSLC 2
#define NPC 3
#define ETL 4
#define NCHA 4
#define NX 128
#define NY 128
#define NLIN 128
#define NCOL 256
#define NLIN_PE 32            // lines per echo
#define NB 8                  // nslc*ncha
#define NTILE 64              // 16-row tiles per echo

typedef __attribute__((ext_vector_type(8))) short short8;
typedef __attribute__((ext_vector_type(4))) float float4_t;

#define AS1 __attribute__((address_space(1)))
#define AS3 __attribute__((address_space(3)))

static __device__ __forceinline__ unsigned short f2bf(float f) {
  unsigned u = __float_as_uint(f);
  unsigned r = (u + 0x7FFFu + ((u >> 16) & 1u)) >> 16;
  return (unsigned short)r;
}

// ---------------------------------------------------------------------------
// A layout (bf16 elements): addr = (e*64 + rt)*4096 + g*128 + r*8 + j
//   row = rt*16 + r   (row = b*NX + x  ->  rt = b*8 + (x>>4), r = x&15)
//   k   = g*8 + j     (k<128: Re(coil) at y=k ; k>=128: Im at y=k-128)
// UNCHANGED (verified R3/R7).
// ---------------------------------------------------------------------------
__global__ __launch_bounds__(256) void prep_coil(
    const float* __restrict__ imR, const float* __restrict__ imI,
    const float* __restrict__ smR, const float* __restrict__ smI,
    const float* __restrict__ Dm, unsigned short* __restrict__ A) {
  int tid = blockIdx.x * blockDim.x + threadIdx.x;  // (s, x, y)
  if (tid >= NSLC * NX * NY) return;
  int y = tid & (NY - 1);
  int x = (tid >> 7) & (NX - 1);
  int s = tid >> 14;

  float ir[NPC], ii[NPC];
#pragma unroll
  for (int p = 0; p < NPC; ++p) {
    int idx = ((s * NPC + p) * NX + x) * NY + y;
    ir[p] = imR[idx];
    ii[p] = imI[idx];
  }
  float sr[NCHA], si[NCHA];
#pragma unroll
  for (int c = 0; c < NCHA; ++c) {
    int idx = ((s * NCHA + c) * NX + x) * NY + y;
    sr[c] = smR[idx];
    si[c] = smI[idx];
  }
#pragma unroll
  for (int e = 0; e < ETL; ++e) {
    float gr = 0.f, gi = 0.f;
#pragma unroll
    for (int p = 0; p < NPC; ++p) {
      float d = Dm[(s * ETL + e) * NPC + p];
      gr += d * ir[p];
      gi += d * ii[p];
    }
#pragma unroll
    for (int c = 0; c < NCHA; ++c) {
      int row = (s * NCHA + c) * NX + x;
      int rt = row >> 4;
      float cr = gr * sr[c] - gi * si[c];
      float ci = gr * si[c] + gi * sr[c];
      unsigned short* dst = A + (e * NTILE + rt) * 4096 + (row & 15) * 8 + (y & 7);
      dst[(y >> 3) * 128] = f2bf(cr);
      dst[(16 + (y >> 3)) * 128] = f2bf(ci);
    }
  }
}

// ---------------------------------------------------------------------------
// Main: block = (echo, 16 m-points), 4 waves. R3 skeleton: wave w owns tiles
// rt = w + i*4, i = 0..15 (b = i>>1, x-band = w + 4*(i&1)); private staging.
// R8 changes: (1) B1=[cos;sin] only, quarter-GEMMs X,Y->accR, U,V->accU/V,
// Ti = accV-accU. (2) half-tile 4KB chunks, 3-buffer ring, 2-deep prefetch
// with counted vmcnt(8). LDS 48KB/block -> 3 blocks/CU.
// ---------------------------------------------------------------------------
__global__ __launch_bounds__(256, 3) void radtse_mfma(
    const unsigned short* __restrict__ A, const float* __restrict__ traj,
    const float* __restrict__ mask, float* __restrict__ out) {
  __shared__ __align__(16) char lds[49152];  // 4 waves x 3 x 4 KB private ring

  const int tid = threadIdx.x;
  const int w = tid >> 6;
  const int lane = tid & 63;
  const int e = blockIdx.x >> 9;
  const int m0 = (blockIdx.x & 511) << 4;
  const int lin = e * NLIN_PE + (m0 >> 8);  // all 16 m share one line
  const int mloc = lane & 15;
  const int ksl = lane >> 4;  // k-slice (A/B frag) and D-row group

  const int col = (m0 + mloc) & (NCOL - 1);
  const float kx = traj[(lin * NCOL + col) * 2 + 0];
  const float ky = traj[(lin * NCOL + col) * 2 + 1];

  // ---- B1 = [cos ; sin] fragments: bfr[kk], k = kk*32 + ksl*8 + j ----
  short8 bfr[8];
#pragma unroll
  for (int kk = 0; kk < 8; ++kk) {
    short8 v;
#pragma unroll
    for (int j = 0; j < 8; ++j) {
      const int k = kk * 32 + ksl * 8 + j;
      float sn, cs;
      __sincosf(ky * (float)((k & 127) - 64), &sn, &cs);
      v[j] = (short)f2bf(k < 128 ? cs : sn);
    }
    bfr[kk] = v;
  }

  // ---- ex phase factors: band(par) = w + 4*par, x = band*16 + ksl*4 + r ----
  float exr[2][4], exi[2][4];
#pragma unroll
  for (int par = 0; par < 2; ++par) {
    const int xb = (w + par * 4) * 16 + ksl * 4;
#pragma unroll
    for (int r = 0; r < 4; ++r) {
      float sn, cs;
      __sincosf(kx * (float)(xb + r - 64), &sn, &cs);
      exr[par][r] = cs;
      exi[par][r] = -sn;
    }
  }

  float kr[8], ki[8];
#pragma unroll
  for (int b = 0; b < 8; ++b) {
    kr[b] = 0.f;
    ki[b] = 0.f;
  }

  const char* Ae = (const char*)(A + e * (NTILE * 4096));
  char* mybuf = lds + w * 12288;  // my private 3 x 4 KB ring

  // Chunk c = 2*i + h: half h of tile rt = w + i*4 (4 KB) into ring slot c%3.
  // LDS base wave-uniform (hardware adds lane*16); global source per-lane.
  auto STAGE = [&](int c) {
    const int rt = w + (c >> 1) * 4;
    const char* src = Ae + rt * 8192 + (c & 1) * 4096 + lane * 16;
    char* d = mybuf + (c % 3) * 4096;
#pragma unroll
    for (int j = 0; j < 4; ++j)
      __builtin_amdgcn_global_load_lds((const AS1 unsigned int*)(src + j * 1024),
                                       (AS3 unsigned int*)(d + j * 1024), 16, 0,
                                       0);
  };

  STAGE(0);
  STAGE(1);

#pragma unroll
  for (int i = 0; i < 16; ++i) {
    const int b = i >> 1;    // static under full unroll
    const int par = i & 1;

    float4_t accR = {0.f, 0.f, 0.f, 0.f};
    float4_t accU = {0.f, 0.f, 0.f, 0.f};
    float4_t accV = {0.f, 0.f, 0.f, 0.f};

#pragma unroll
    for (int h = 0; h < 2; ++h) {
      const int c = 2 * i + h;
      // WAR: my ds_reads of chunk c-1 (ring slot (c+2)%3) must be done
      // before overwriting it with chunk c+2.
      asm volatile("s_waitcnt lgkmcnt(0)" ::: "memory");
      if (c + 2 < 32) {
        STAGE(c + 2);
        asm volatile("s_waitcnt vmcnt(8)" ::: "memory");  // chunk c landed
      } else if (c == 30) {
        asm volatile("s_waitcnt vmcnt(4)" ::: "memory");
      } else {
        asm volatile("s_waitcnt vmcnt(0)" ::: "memory");
      }

      const char* ab = mybuf + (c % 3) * 4096 + ksl * 256 + mloc * 16;
      short8 afr[4];
#pragma unroll
      for (int kk = 0; kk < 4; ++kk)
        afr[kk] = *(const short8*)(ab + kk * 1024);

      if (h == 0) {
        // lo K-half = cr rows: X = cr*cos -> accR, U = cr*sin -> accU
#pragma unroll
        for (int kk = 0; kk < 4; ++kk) {
          accR = __builtin_amdgcn_mfma_f32_16x16x32_bf16(afr[kk], bfr[kk], accR,
                                                         0, 0, 0);
          accU = __builtin_amdgcn_mfma_f32_16x16x32_bf16(afr[kk], bfr[kk + 4],
                                                         accU, 0, 0, 0);
        }
      } else {
        // hi K-half = ci rows: Y = ci*sin -> accR, V = ci*cos -> accV
#pragma unroll
        for (int kk = 0; kk < 4; ++kk) {
          accR = __builtin_amdgcn_mfma_f32_16x16x32_bf16(afr[kk], bfr[kk + 4],
                                                         accR, 0, 0, 0);
          accV = __builtin_amdgcn_mfma_f32_16x16x32_bf16(afr[kk], bfr[kk], accV,
                                                         0, 0, 0);
        }
      }
    }

    // fold: Tr = accR, Ti = accV - accU; x-band = w + 4*par
#pragma unroll
    for (int r = 0; r < 4; ++r) {
      const float tr = accR[r];
      const float ti = accV[r] - accU[r];
      kr[b] += tr * exr[par][r] - ti * exi[par][r];
      ki[b] += tr * exi[par][r] + ti * exr[par][r];
    }
  }

  // ---- reduce over D-row groups (xor 16/32 preserves mloc) ----
#pragma unroll
  for (int b = 0; b < 8; ++b) {
    kr[b] += __shfl_xor(kr[b], 16, 64);
    kr[b] += __shfl_xor(kr[b], 32, 64);
    ki[b] += __shfl_xor(ki[b], 16, 64);
    ki[b] += __shfl_xor(ki[b], 32, 64);
  }

  // ---- cross-wave combine (R3-verbatim, drained barrier first) ----
  asm volatile("s_waitcnt vmcnt(0) lgkmcnt(0)" ::: "memory");
  __syncthreads();
  float* comb = (float*)lds;  // 4 KB reuse
#pragma unroll
  for (int b = 0; b < 8; ++b) {
    if (lane < 16) {
      comb[((w * 16 + lane) * 8 + b) * 2 + 0] = kr[b];
      comb[((w * 16 + lane) * 8 + b) * 2 + 1] = ki[b];
    }
  }
  __syncthreads();
  {
    const int m_l = tid >> 4;
    const int b = (tid >> 1) & 7;
    const int ri = tid & 1;
    float v = 0.f;
#pragma unroll
    for (int ww = 0; ww < 4; ++ww) v += comb[((ww * 16 + m_l) * 8 + b) * 2 + ri];
    const int colw = (m0 + m_l) & (NCOL - 1);
    const int s = b >> 2;
    const float mv = mask[(s * NLIN + lin) * NCOL + colw];
    out[((b * NLIN + lin) * NCOL + colw) * 2 + ri] = v * mv;
  }
}

extern "C" void kernel_launch(void* const* d_in, const int* in_sizes, int n_in,
                              void* d_out, int out_size, void* d_ws, size_t ws_size,
                              hipStream_t stream) {
  const float* imR = (const float*)d_in[0];
  const float* imI = (const float*)d_in[1];
  const float* smR = (const float*)d_in[2];
  const float* smI = (const float*)d_in[3];
  const float* Dm = (const float*)d_in[4];
  const float* mask = (const float*)d_in[5];
  const float* traj = (const float*)d_in[6];
  float* out = (float*)d_out;
  unsigned short* A = (unsigned short*)d_ws;  // 2 MB: [ETL][64 tiles][4096]

  prep_coil<<<dim3(NSLC * NX * NY / 256), dim3(256), 0, stream>>>(imR, imI, smR,
                                                                  smI, Dm, A);
  radtse_mfma<<<dim3(ETL * 512), dim3(256), 0, stream>>>(A, traj, mask, out);
}

// Round 11
// 70.748 us; speedup vs baseline: 1.4201x; 1.4201x over previous
//
#include <hip/hip_runtime.h>
#include <math.h>

#define NSLC 2
#define NPC 3
#define ETL 4
#define NCHA 4
#define NX 128
#define NY 128
#define NLIN 128
#define NCOL 256
#define NLIN_PE 32            // lines per echo
#define NB 8                  // nslc*ncha
#define NTILE 64              // 16-row tiles per echo

typedef __attribute__((ext_vector_type(8))) short short8;
typedef __attribute__((ext_vector_type(4))) float float4_t;

#define AS1 __attribute__((address_space(1)))
#define AS3 __attribute__((address_space(3)))

static __device__ __forceinline__ unsigned short f2bf(float f) {
  unsigned u = __float_as_uint(f);
  unsigned r = (u + 0x7FFFu + ((u >> 16) & 1u)) >> 16;
  return (unsigned short)r;
}

// ---------------------------------------------------------------------------
// A layout (bf16 elements): addr = (e*64 + rt)*4096 + g*128 + r*8 + j
//   row = rt*16 + r   (row = b*NX + x  ->  rt = b*8 + (x>>4), r = x&15)
//   k   = g*8 + j     (k<128: Re(coil) at y=k ; k>=128: Im at y=k-128)
// UNCHANGED (verified R3/R7/R8).
// ---------------------------------------------------------------------------
__global__ __launch_bounds__(256) void prep_coil(
    const float* __restrict__ imR, const float* __restrict__ imI,
    const float* __restrict__ smR, const float* __restrict__ smI,
    const float* __restrict__ Dm, unsigned short* __restrict__ A) {
  int tid = blockIdx.x * blockDim.x + threadIdx.x;  // (s, x, y)
  if (tid >= NSLC * NX * NY) return;
  int y = tid & (NY - 1);
  int x = (tid >> 7) & (NX - 1);
  int s = tid >> 14;

  float ir[NPC], ii[NPC];
#pragma unroll
  for (int p = 0; p < NPC; ++p) {
    int idx = ((s * NPC + p) * NX + x) * NY + y;
    ir[p] = imR[idx];
    ii[p] = imI[idx];
  }
  float sr[NCHA], si[NCHA];
#pragma unroll
  for (int c = 0; c < NCHA; ++c) {
    int idx = ((s * NCHA + c) * NX + x) * NY + y;
    sr[c] = smR[idx];
    si[c] = smI[idx];
  }
#pragma unroll
  for (int e = 0; e < ETL; ++e) {
    float gr = 0.f, gi = 0.f;
#pragma unroll
    for (int p = 0; p < NPC; ++p) {
      float d = Dm[(s * ETL + e) * NPC + p];
      gr += d * ir[p];
      gi += d * ii[p];
    }
#pragma unroll
    for (int c = 0; c < NCHA; ++c) {
      int row = (s * NCHA + c) * NX + x;
      int rt = row >> 4;
      float cr = gr * sr[c] - gi * si[c];
      float ci = gr * si[c] + gi * sr[c];
      unsigned short* dst = A + (e * NTILE + rt) * 4096 + (row & 15) * 8 + (y & 7);
      dst[(y >> 3) * 128] = f2bf(cr);
      dst[(16 + (y >> 3)) * 128] = f2bf(ci);
    }
  }
}

// ---------------------------------------------------------------------------
// Main (R11 = R3 + 4KB/3-slot ring): block = (echo, 16 m), 4 waves.
// Wave w owns tiles rt = w + i*4 (b = i>>1, x-band par = i&1), staged as
// 32 half-tile chunks (4 KB) into a private 3-slot ring (12 KB/wave,
// 48 KB/block -> 3 blocks/CU). R8-validated waits: lgkmcnt(0) WAR guard,
// counted vmcnt(8)/(4)/(0). Full-B math (R3): accR/accI accumulate across
// the two K-halves; bfr[ct][h*4+kk] k-aligns with the half's afr[kk].
// NO barriers in the main loop, no cross-wave sharing of staged data.
// ---------------------------------------------------------------------------
__global__ __launch_bounds__(256) void radtse_mfma(
    const unsigned short* __restrict__ A, const float* __restrict__ traj,
    const float* __restrict__ mask, float* __restrict__ out) {
  __shared__ __align__(16) char lds[49152];  // 4 waves x 3 x 4 KB ring

  const int tid = threadIdx.x;
  const int w = tid >> 6;
  const int lane = tid & 63;
  const int e = blockIdx.x >> 9;
  const int m0 = (blockIdx.x & 511) << 4;
  const int lin = e * NLIN_PE + (m0 >> 8);  // all 16 m share one line
  const int mloc = lane & 15;
  const int ksl = lane >> 4;  // k-slice (A/B frag) and D-row group

  // ---- build B in lds[0..16KB): Tr group at g*256 + m*16, Ti at +8192 ----
  {
    const int m = tid & 15;
    const int g0 = (tid >> 4) * 2;
    const int col = (m0 + m) & (NCOL - 1);
    const float ky = traj[(lin * NCOL + col) * 2 + 1];
#pragma unroll
    for (int gg = 0; gg < 2; ++gg) {
      const int g = g0 + gg;
      short8 vr, vi;
#pragma unroll
      for (int j = 0; j < 8; ++j) {
        const int k = g * 8 + j;
        float sn, cs;
        __sincosf(ky * (float)((k & 127) - 64), &sn, &cs);
        vr[j] = (short)f2bf((k < 128) ? cs : sn);   // Tr col: [cos ; +sin]
        vi[j] = (short)f2bf((k < 128) ? -sn : cs);  // Ti col: [-sin ; cos]
      }
      *(short8*)(lds + g * 256 + m * 16) = vr;
      *(short8*)(lds + 8192 + g * 256 + m * 16) = vi;
    }
  }

  // ---- ex phase factors in registers (R3-verbatim) ----
  float exr[2][4], exi[2][4];
  {
    const int col = (m0 + mloc) & (NCOL - 1);
    const float kx = traj[(lin * NCOL + col) * 2 + 0];
#pragma unroll
    for (int par = 0; par < 2; ++par) {
      const int xb = (w + par * 4) * 16 + ksl * 4;
#pragma unroll
      for (int r = 0; r < 4; ++r) {
        float sn, cs;
        __sincosf(kx * (float)(xb + r - 64), &sn, &cs);
        exr[par][r] = cs;
        exi[par][r] = -sn;
      }
    }
  }
  __syncthreads();

  // ---- hoist B fragments (conflict-free: lane*16 contiguous) ----
  short8 bfr[2][8];
#pragma unroll
  for (int ct = 0; ct < 2; ++ct)
#pragma unroll
    for (int kk = 0; kk < 8; ++kk)
      bfr[ct][kk] = *(const short8*)(lds + ct * 8192 + kk * 1024 + lane * 16);
  __syncthreads();  // all waves done reading B; region reused for ring

  float kr[8], ki[8];
#pragma unroll
  for (int b = 0; b < 8; ++b) {
    kr[b] = 0.f;
    ki[b] = 0.f;
  }

  const char* Ae = (const char*)(A + e * (NTILE * 4096));
  char* mybuf = lds + w * 12288;  // my private 3 x 4 KB ring

  // Chunk c = 2*i + h: K-half h of tile rt = w + i*4 (4 KB) into slot c%3.
  // LDS base wave-uniform (hardware adds lane*16); global source per-lane.
  auto STAGE = [&](int c) {
    const int rt = w + (c >> 1) * 4;
    const char* src = Ae + rt * 8192 + (c & 1) * 4096 + lane * 16;
    char* d = mybuf + (c % 3) * 4096;
#pragma unroll
    for (int j = 0; j < 4; ++j)
      __builtin_amdgcn_global_load_lds((const AS1 unsigned int*)(src + j * 1024),
                                       (AS3 unsigned int*)(d + j * 1024), 16, 0,
                                       0);
  };

  STAGE(0);
  STAGE(1);

#pragma unroll
  for (int i = 0; i < 16; ++i) {
    const int b = i >> 1;    // static under full unroll
    const int par = i & 1;

    float4_t accR = {0.f, 0.f, 0.f, 0.f};
    float4_t accI = {0.f, 0.f, 0.f, 0.f};

#pragma unroll
    for (int h = 0; h < 2; ++h) {
      const int c = 2 * i + h;
      // WAR: my ds_reads of chunk c-1 (slot (c+2)%3) done before overwrite
      asm volatile("s_waitcnt lgkmcnt(0)" ::: "memory");
      if (c + 2 < 32) {
        STAGE(c + 2);
        asm volatile("s_waitcnt vmcnt(8)" ::: "memory");  // chunk c landed
      } else if (c == 30) {
        asm volatile("s_waitcnt vmcnt(4)" ::: "memory");
      } else {
        asm volatile("s_waitcnt vmcnt(0)" ::: "memory");
      }

      const char* ab = mybuf + (c % 3) * 4096 + ksl * 256 + mloc * 16;
      short8 afr[4];
#pragma unroll
      for (int kk = 0; kk < 4; ++kk)
        afr[kk] = *(const short8*)(ab + kk * 1024);

#pragma unroll
      for (int kk = 0; kk < 4; ++kk) {
        accR = __builtin_amdgcn_mfma_f32_16x16x32_bf16(afr[kk],
                                                       bfr[0][h * 4 + kk], accR,
                                                       0, 0, 0);
        accI = __builtin_amdgcn_mfma_f32_16x16x32_bf16(afr[kk],
                                                       bfr[1][h * 4 + kk], accI,
                                                       0, 0, 0);
      }
    }

    // fold: x = (w + par*4)*16 + ksl*4 + r; Tr = accR, Ti = accI
#pragma unroll
    for (int r = 0; r < 4; ++r) {
      kr[b] += accR[r] * exr[par][r] - accI[r] * exi[par][r];
      ki[b] += accR[r] * exi[par][r] + accI[r] * exr[par][r];
    }
  }

  // ---- reduce over D-row groups (xor 16/32 preserves mloc) ----
#pragma unroll
  for (int b = 0; b < 8; ++b) {
    kr[b] += __shfl_xor(kr[b], 16, 64);
    kr[b] += __shfl_xor(kr[b], 32, 64);
    ki[b] += __shfl_xor(ki[b], 16, 64);
    ki[b] += __shfl_xor(ki[b], 32, 64);
  }

  // ---- cross-wave combine (R3-verbatim, drained barrier first) ----
  asm volatile("s_waitcnt vmcnt(0) lgkmcnt(0)" ::: "memory");
  __syncthreads();
  float* comb = (float*)lds;  // 4 KB reuse
#pragma unroll
  for (int b = 0; b < 8; ++b) {
    if (lane < 16) {
      comb[((w * 16 + lane) * 8 + b) * 2 + 0] = kr[b];
      comb[((w * 16 + lane) * 8 + b) * 2 + 1] = ki[b];
    }
  }
  __syncthreads();
  {
    const int m_l = tid >> 4;
    const int b = (tid >> 1) & 7;
    const int ri = tid & 1;
    float v = 0.f;
#pragma unroll
    for (int ww = 0; ww < 4; ++ww) v += comb[((ww * 16 + m_l) * 8 + b) * 2 + ri];
    const int colw = (m0 + m_l) & (NCOL - 1);
    const int s = b >> 2;
    const float mv = mask[(s * NLIN + lin) * NCOL + colw];
    out[((b * NLIN + lin) * NCOL + colw) * 2 + ri] = v * mv;
  }
}

extern "C" void kernel_launch(void* const* d_in, const int* in_sizes, int n_in,
                              void* d_out, int out_size, void* d_ws, size_t ws_size,
                              hipStream_t stream) {
  const float* imR = (const float*)d_in[0];
  const float* imI = (const float*)d_in[1];
  const float* smR = (const float*)d_in[2];
  const float* smI = (const float*)d_in[3];
  const float* Dm = (const float*)d_in[4];
  const float* mask = (const float*)d_in[5];
  const float* traj = (const float*)d_in[6];
  float* out = (float*)d_out;
  unsigned short* A = (unsigned short*)d_ws;  // 2 MB: [ETL][64 tiles][4096]

  prep_coil<<<dim3(NSLC * NX * NY / 256), dim3(256), 0, stream>>>(imR, imI, smR,
                                                                  smI, Dm, A);
  radtse_mfma<<<dim3(ETL * 512), dim3(256), 0, stream>>>(A, traj, mask, out);
}